// Round 4
// baseline (107.482 us; speedup 1.0000x reference)
//
#include <hip/hip_runtime.h>
#include <hip/hip_bf16.h>
#include <stdint.h>

#define K_DIM 1024
#define N_DIM 1024
#define NKT 16   // K / 64 K-tiles

typedef __attribute__((ext_vector_type(8))) short  short8;
typedef __attribute__((ext_vector_type(4))) float  f32x4;
typedef __attribute__((ext_vector_type(4))) unsigned int u32x4;

__device__ __forceinline__ ushort f2bf(float f) {
  union { float f; uint32_t u; } v; v.f = f;
  uint32_t r = v.u + 0x7FFFu + ((v.u >> 16) & 1u);
  return (ushort)(r >> 16);
}
__device__ __forceinline__ uint32_t pack_bf2(float a, float b) {
  __hip_bfloat162 h = __float22bfloat162_rn(make_float2(a, b));
  union { __hip_bfloat162 h; uint32_t u; } c; c.h = h;
  return c.u;
}

// ---------------- kernel 1: materialize Toeplitz matrix as bf16 -------------
__global__ __launch_bounds__(256) void build_T_kernel(
    const float* __restrict__ fr, const float* __restrict__ fc,
    ushort* __restrict__ T) {
  int idx = blockIdx.x * 256 + threadIdx.x;
  int o  = idx >> 7;
  int i0 = (idx & 127) << 3;
  short8 v;
#pragma unroll
  for (int j = 0; j < 8; ++j) {
    int d = o - (i0 + j);
    float f = (d >= 0) ? fc[d] : fr[-d];
    v[j] = (short)f2bf(f);
  }
  *reinterpret_cast<short8*>(T + (size_t)idx * 8) = v;
}

// ---------------- kernel 2: 256x256, 4-phase/K-tile, counted vmcnt ----------
__global__ __launch_bounds__(512, 2) void toeplitz_gemm(
    const float* __restrict__ X, const ushort* __restrict__ T,
    const float* __restrict__ bias, float* __restrict__ Out) {
  // LDS: A dbuf [2][32KB] @0, B dbuf [2][32KB] @64KB  => 128 KiB
  __shared__ alignas(16) char smem[131072];

  const int tid  = threadIdx.x;
  const int lane = tid & 63;
  const int wv   = tid >> 6;
  const int wr   = wv >> 2;          // 0..1 (m)
  const int wn   = wv & 3;           // 0..3 (n)
  const int cc   = lane & 15, kg = lane >> 4;

  // XCD swizzle: 512 blocks = 8 XCD x 64; consecutive swz share m-panel.
  const int swz = (blockIdx.x & 7) * 64 + (blockIdx.x >> 3);
  const int m0 = (swz >> 2) * 256;
  const int n0 = (swz & 3) * 256;

  // ---- B staging (global_load_lds, pre-swizzled source) ----
  const int brow = tid >> 3;
  const ushort* tptr = T + (size_t)(n0 + brow) * K_DIM
                         + ((((tid & 7) * 16) ^ ((brow & 7) << 4)) >> 1);
  const int bLds = 65536 + tid * 16;                 // + sel*32768 + g*8192

  // ---- A staging (reg-stage fp32 -> bf16, swizzled ds_write_b128) ----
  const float* xptr = X + (size_t)(m0 + (tid >> 3)) * K_DIM + (tid & 7) * 8;
  const int aW = (tid >> 3) * 128
               + ((16 * (tid & 7)) ^ (((tid >> 3) & 7) << 4)); // +sel*32768+i*8192

  const int aXor = (cc & 7) << 4;

  f32x4  areg[8];
  short8 afr[4][2];     // current mf-quadrant (mfb..mfb+3) x kk
  short8 bfr[2][2];     // current nf-pair x kk
  f32x4  acc[8][4] = {};

#define SB0() __builtin_amdgcn_sched_barrier(0)
#define BARRIER() __builtin_amdgcn_s_barrier()
#define LGKM0() asm volatile("s_waitcnt lgkmcnt(0)" ::: "memory")

#define ISSUE_A(t)                                                          \
  { _Pragma("unroll")                                                       \
    for (int i = 0; i < 4; ++i)                                             \
      _Pragma("unroll")                                                     \
      for (int j = 0; j < 2; ++j)                                           \
        areg[i * 2 + j] = *reinterpret_cast<const f32x4*>(                  \
            xptr + (size_t)i * 64 * K_DIM + (t) * 64 + j * 4); }

#define ISSUE_B(t, sel)                                                     \
  { _Pragma("unroll")                                                       \
    for (int g = 0; g < 4; ++g) {                                           \
      const ushort* src = tptr + (size_t)g * 64 * K_DIM + (t) * 64;         \
      char* dst = smem + bLds + (sel) * 32768 + g * 8192;                   \
      __builtin_amdgcn_global_load_lds(                                     \
          (const __attribute__((address_space(1))) void*)src,               \
          (__attribute__((address_space(3))) void*)dst, 16, 0, 0);          \
    } }

#define WRITE_A(sel)                                                        \
  { _Pragma("unroll")                                                       \
    for (int i = 0; i < 4; ++i) {                                           \
      u32x4 p;                                                              \
      p.x = pack_bf2(areg[2*i].x, areg[2*i].y);                             \
      p.y = pack_bf2(areg[2*i].z, areg[2*i].w);                             \
      p.z = pack_bf2(areg[2*i+1].x, areg[2*i+1].y);                         \
      p.w = pack_bf2(areg[2*i+1].z, areg[2*i+1].w);                         \
      *reinterpret_cast<u32x4*>(smem + (sel) * 32768 + aW + i * 8192) = p;  \
    } }

#define READ_AFR(sel, mfb)                                                  \
  { _Pragma("unroll")                                                       \
    for (int mf = 0; mf < 4; ++mf)                                          \
      _Pragma("unroll")                                                     \
      for (int kk = 0; kk < 2; ++kk)                                        \
        afr[mf][kk] = *reinterpret_cast<const short8*>(                     \
            smem + (sel) * 32768 +                                          \
            (wr * 128 + ((mfb) + mf) * 16 + cc) * 128 +                     \
            ((kk * 64 + kg * 16) ^ aXor)); }

#define READ_BFR(sel, nfb)                                                  \
  { _Pragma("unroll")                                                       \
    for (int nf = 0; nf < 2; ++nf)                                          \
      _Pragma("unroll")                                                     \
      for (int kk = 0; kk < 2; ++kk)                                        \
        bfr[nf][kk] = *reinterpret_cast<const short8*>(                     \
            smem + 65536 + (sel) * 32768 +                                  \
            (wn * 64 + ((nfb) + nf) * 16 + cc) * 128 +                      \
            ((kk * 64 + kg * 16) ^ aXor)); }

#define MFMA_Q(mfb, nfb)                                                    \
  { __builtin_amdgcn_s_setprio(1);                                         \
    _Pragma("unroll")                                                       \
    for (int mf = 0; mf < 4; ++mf)                                          \
      _Pragma("unroll")                                                     \
      for (int nf = 0; nf < 2; ++nf)                                        \
        _Pragma("unroll")                                                   \
        for (int kk = 0; kk < 2; ++kk)                                      \
          acc[(mfb) + mf][(nfb) + nf] = __builtin_amdgcn_mfma_f32_16x16x32_bf16( \
              afr[mf][kk], bfr[nf][kk], acc[(mfb) + mf][(nfb) + nf], 0, 0, 0);   \
    __builtin_amdgcn_s_setprio(0); }

#define PHASE_TAIL(mfb, nfb)                                                \
  BARRIER(); LGKM0(); SB0();                                                \
  MFMA_Q(mfb, nfb);

  // ---- prologue: stage K-tile 0 into buf0, prefetch A(1) into regs ----
  ISSUE_B(0, 0); SB0();
  ISSUE_A(0);    SB0();
  WRITE_A(0);                 // implicit vmcnt wait for A(0) (drains B(0) too)
  ISSUE_A(1);                 // A for K-tile 1 (consumed in iter 0's WRITE_A)
  LGKM0();
  BARRIER();

#pragma unroll 1
  for (int t = 0; t < NKT; ++t) {
    const int c = t & 1, n = c ^ 1;
    // ---- P1: staging (pinned VM order: B then A), afr(0-3)+bfr(0-1) ----
    if (t < NKT - 1) { ISSUE_B(t + 1, n); SB0(); WRITE_A(n); SB0(); }
    if (t < NKT - 2) { ISSUE_A(t + 2); SB0(); }
    READ_AFR(c, 0); READ_BFR(c, 0);
    PHASE_TAIL(0, 0);
    BARRIER();
    // ---- P2: bfr(2-3), afr reused ----
    READ_BFR(c, 2);
    PHASE_TAIL(0, 2);
    BARRIER();
    // ---- P3: afr(4-7), bfr reused ----
    READ_AFR(c, 4);
    PHASE_TAIL(4, 2);
    BARRIER();
    // ---- P4: bfr(0-1) re-read; counted vmcnt gate before final barrier ----
    READ_BFR(c, 0);
    PHASE_TAIL(4, 0);
    if (t < NKT - 2) { asm volatile("s_waitcnt vmcnt(8)" ::: "memory"); }
    else             { asm volatile("s_waitcnt vmcnt(0)" ::: "memory"); }
    BARRIER();
  }

  // ---- epilogue: bias + fp32 store ----
#pragma unroll
  for (int nf = 0; nf < 4; ++nf) {
    const int col = n0 + wn * 64 + nf * 16 + cc;
    const float bv = bias[col];
#pragma unroll
    for (int mf = 0; mf < 8; ++mf) {
      const int row0 = m0 + wr * 128 + mf * 16 + kg * 4;
      float* op = Out + (size_t)row0 * N_DIM + col;
#pragma unroll
      for (int j = 0; j < 4; ++j)
        op[(size_t)j * N_DIM] = acc[mf][nf][j] + bv;
    }
  }
#undef ISSUE_A
#undef ISSUE_B
#undef WRITE_A
#undef READ_AFR
#undef READ_BFR
#undef MFMA_Q
#undef PHASE_TAIL
#undef SB0
#undef BARRIER
#undef LGKM0
}

// ---------------- fallback (ws too small): naive fp32 ----------------------
__global__ __launch_bounds__(256) void toeplitz_naive(
    const float* __restrict__ x, const float* __restrict__ fr,
    const float* __restrict__ fc, const float* __restrict__ bias,
    float* __restrict__ out) {
  __shared__ float sx[1024], sfr[1024], sfc[1024];
  const int m = blockIdx.x;
  for (int i = threadIdx.x; i < 1024; i += 256) {
    sx[i]  = x[(size_t)m * 1024 + i];
    sfr[i] = fr[i];
    sfc[i] = fc[i];
  }
  __syncthreads();
  for (int q = 0; q < 4; ++q) {
    const int o = threadIdx.x + q * 256;
    float acc = bias[o];
    for (int i = 0; i <= o; ++i)       acc += sx[i] * sfc[o - i];
    for (int i = o + 1; i < 1024; ++i) acc += sx[i] * sfr[i - o];
    out[(size_t)m * 1024 + o] = acc;
  }
}

extern "C" void kernel_launch(void* const* d_in, const int* in_sizes, int n_in,
                              void* d_out, int out_size, void* d_ws, size_t ws_size,
                              hipStream_t stream) {
  const float* x    = (const float*)d_in[0];
  const float* fr   = (const float*)d_in[1];
  const float* fc   = (const float*)d_in[2];
  const float* bias = (const float*)d_in[3];
  float* out = (float*)d_out;

  if (ws_size >= (size_t)2 * 1024 * 1024) {
    ushort* T = (ushort*)d_ws;
    build_T_kernel<<<dim3(512), dim3(256), 0, stream>>>(fr, fc, T);
    toeplitz_gemm<<<dim3(512), dim3(512), 0, stream>>>(x, T, bias, out);
  } else {
    toeplitz_naive<<<dim3(32768), dim3(256), 0, stream>>>(x, fr, fc, bias, out);
  }
}

// Round 5
// 106.619 us; speedup vs baseline: 1.0081x; 1.0081x over previous
//
#include <hip/hip_runtime.h>
#include <hip/hip_bf16.h>
#include <stdint.h>

#define K_DIM 1024
#define N_DIM 1024
#define NKT 16   // K / 64

typedef __attribute__((ext_vector_type(8))) short  short8;
typedef __attribute__((ext_vector_type(4))) float  f32x4;

__device__ __forceinline__ ushort f2bf(float f) {
  union { float f; uint32_t u; } v; v.f = f;
  uint32_t r = v.u + 0x7FFFu + ((v.u >> 16) & 1u);
  return (ushort)(r >> 16);
}
__device__ __forceinline__ uint32_t pack_bf2(float a, float b) {
  __hip_bfloat162 h = __float22bfloat162_rn(make_float2(a, b));
  union { __hip_bfloat162 h; uint32_t u; } c; c.h = h;
  return c.u;
}

// ---------------- kernel 1: materialize Toeplitz matrix as bf16 -------------
__global__ __launch_bounds__(256) void build_T_kernel(
    const float* __restrict__ fr, const float* __restrict__ fc,
    ushort* __restrict__ T) {
  int idx = blockIdx.x * 256 + threadIdx.x;
  int o  = idx >> 7;
  int i0 = (idx & 127) << 3;
  short8 v;
#pragma unroll
  for (int j = 0; j < 8; ++j) {
    int d = o - (i0 + j);
    float f = (d >= 0) ? fc[d] : fr[-d];
    v[j] = (short)f2bf(f);
  }
  *reinterpret_cast<short8*>(T + (size_t)idx * 8) = v;
}

// --------- kernel 2: 256x256; A direct global->reg; B LDS dbuf -------------
// 8 m-waves x 32 rows each; 1 barrier + 1 counted vmcnt per K-tile.
__global__ __launch_bounds__(512, 2) void toeplitz_gemm(
    const float* __restrict__ X, const ushort* __restrict__ T,
    const float* __restrict__ bias, float* __restrict__ Out) {
  __shared__ alignas(16) char smem[65536];   // B dbuf: 2 x 32 KiB

  const int tid  = threadIdx.x;
  const int lane = tid & 63;
  const int wv   = tid >> 6;                 // m-wave 0..7
  const int cc   = lane & 15, kg = lane >> 4;

  // XCD swizzle: 512 blocks = 8 XCD x 64; consecutive swz share m-panel.
  const int swz = (blockIdx.x & 7) * 64 + (blockIdx.x >> 3);
  const int m0 = (swz >> 2) * 256;
  const int n0 = (swz & 3) * 256;

  // ---- B staging (global_load_lds, pre-swizzled source) ----
  const int brow = tid >> 3;                 // + g*64
  const ushort* tptr = T + (size_t)(n0 + brow) * K_DIM
                         + ((((tid & 7) * 16) ^ ((brow & 7) << 4)) >> 1);
  const int bLds = tid * 16;                 // + sel*32768 + g*8192

  // ---- A direct-to-reg: lane's base row/k ----
  const float* xptr = X + (size_t)(m0 + wv * 32 + cc) * K_DIM + kg * 8;

  const int bXor = (cc & 7) << 4;

  f32x4  areg[2][2][2];     // mf, kk, j  (32 VGPR)
  short8 afrag[2][2];       // mf, kk     (16 VGPR)
  short8 bfr[2][2][2];      // set, nf, kk (32 VGPR)
  f32x4  acc[2][16] = {};   // mf, nf (128, in AGPR)

#define SB0() __builtin_amdgcn_sched_barrier(0)

#define ISSUE_A(t)                                                          \
  { _Pragma("unroll")                                                       \
    for (int mf = 0; mf < 2; ++mf)                                          \
      _Pragma("unroll")                                                     \
      for (int kk = 0; kk < 2; ++kk)                                        \
        _Pragma("unroll")                                                   \
        for (int j = 0; j < 2; ++j)                                         \
          areg[mf][kk][j] = *reinterpret_cast<const f32x4*>(                \
              xptr + (size_t)mf * 16 * K_DIM + (t) * 64 + kk * 32 + j * 4); }

#define CVT_A()                                                             \
  { _Pragma("unroll")                                                       \
    for (int mf = 0; mf < 2; ++mf)                                          \
      _Pragma("unroll")                                                     \
      for (int kk = 0; kk < 2; ++kk) {                                      \
        union { short8 s; uint32_t u[4]; } t_;                              \
        t_.u[0] = pack_bf2(areg[mf][kk][0].x, areg[mf][kk][0].y);           \
        t_.u[1] = pack_bf2(areg[mf][kk][0].z, areg[mf][kk][0].w);           \
        t_.u[2] = pack_bf2(areg[mf][kk][1].x, areg[mf][kk][1].y);           \
        t_.u[3] = pack_bf2(areg[mf][kk][1].z, areg[mf][kk][1].w);           \
        afrag[mf][kk] = t_.s;                                               \
      } }

#define ISSUE_B(t, sel)                                                     \
  { _Pragma("unroll")                                                       \
    for (int g = 0; g < 4; ++g) {                                           \
      const ushort* src = tptr + (size_t)g * 64 * K_DIM + (t) * 64;         \
      char* dst = smem + bLds + (sel) * 32768 + g * 8192;                   \
      __builtin_amdgcn_global_load_lds(                                     \
          (const __attribute__((address_space(1))) void*)src,               \
          (__attribute__((address_space(3))) void*)dst, 16, 0, 0);          \
    } }

#define READ_B(sel, nfg, set)                                               \
  { _Pragma("unroll")                                                       \
    for (int nf = 0; nf < 2; ++nf)                                          \
      _Pragma("unroll")                                                     \
      for (int kk = 0; kk < 2; ++kk)                                        \
        bfr[set][nf][kk] = *reinterpret_cast<const short8*>(                \
            smem + (sel) * 32768 +                                          \
            (((nfg) * 2 + nf) * 16 + cc) * 128 +                            \
            ((kk * 64 + kg * 16) ^ bXor)); }

#define MFMA_G(nfg, set)                                                    \
  { __builtin_amdgcn_s_setprio(1);                                         \
    _Pragma("unroll")                                                       \
    for (int mf = 0; mf < 2; ++mf)                                          \
      _Pragma("unroll")                                                     \
      for (int nf = 0; nf < 2; ++nf)                                        \
        _Pragma("unroll")                                                   \
        for (int kk = 0; kk < 2; ++kk)                                      \
          acc[mf][(nfg) * 2 + nf] = __builtin_amdgcn_mfma_f32_16x16x32_bf16( \
              afrag[mf][kk], bfr[set][nf][kk], acc[mf][(nfg) * 2 + nf],      \
              0, 0, 0);                                                      \
    __builtin_amdgcn_s_setprio(0); }

  // ---- prologue: stage B(0), issue A(0) ----
  ISSUE_B(0, 0); SB0();
  ISSUE_A(0);    SB0();
  asm volatile("s_waitcnt vmcnt(8)" ::: "memory");   // drain B(0), keep A(0)
  __builtin_amdgcn_s_barrier();

#pragma unroll 1
  for (int t = 0; t < NKT; ++t) {
    const int c = t & 1, n = c ^ 1;
    if (t + 1 < NKT) { ISSUE_B(t + 1, n); SB0(); }
    CVT_A();                         // waits A(t) via compiler counted vmcnt
    if (t + 1 < NKT) { ISSUE_A(t + 1); SB0(); }
    READ_B(c, 0, 0);
#pragma unroll
    for (int g = 0; g < 8; ++g) {
      if (g < 7) READ_B(c, g + 1, (g + 1) & 1);
      MFMA_G(g, g & 1);
    }
    if (t + 1 < NKT) {
      asm volatile("s_waitcnt vmcnt(8)" ::: "memory"); // drain B(t+1) DMAs
      __builtin_amdgcn_s_barrier();
    }
  }

  // ---- epilogue: bias + fp32 store ----
#pragma unroll
  for (int nf = 0; nf < 16; ++nf) {
    const int col = n0 + nf * 16 + cc;
    const float bv = bias[col];
#pragma unroll
    for (int mf = 0; mf < 2; ++mf) {
      const int row0 = m0 + wv * 32 + mf * 16 + kg * 4;
      float* op = Out + (size_t)row0 * N_DIM + col;
#pragma unroll
      for (int j = 0; j < 4; ++j)
        op[(size_t)j * N_DIM] = acc[mf][nf][j] + bv;
    }
  }
#undef ISSUE_A
#undef CVT_A
#undef ISSUE_B
#undef READ_B
#undef MFMA_G
#undef SB0
}

// ---------------- fallback (ws too small): naive fp32 ----------------------
__global__ __launch_bounds__(256) void toeplitz_naive(
    const float* __restrict__ x, const float* __restrict__ fr,
    const float* __restrict__ fc, const float* __restrict__ bias,
    float* __restrict__ out) {
  __shared__ float sx[1024], sfr[1024], sfc[1024];
  const int m = blockIdx.x;
  for (int i = threadIdx.x; i < 1024; i += 256) {
    sx[i]  = x[(size_t)m * 1024 + i];
    sfr[i] = fr[i];
    sfc[i] = fc[i];
  }
  __syncthreads();
  for (int q = 0; q < 4; ++q) {
    const int o = threadIdx.x + q * 256;
    float acc = bias[o];
    for (int i = 0; i <= o; ++i)       acc += sx[i] * sfc[o - i];
    for (int i = o + 1; i < 1024; ++i) acc += sx[i] * sfr[i - o];
    out[(size_t)m * 1024 + o] = acc;
  }
}

extern "C" void kernel_launch(void* const* d_in, const int* in_sizes, int n_in,
                              void* d_out, int out_size, void* d_ws, size_t ws_size,
                              hipStream_t stream) {
  const float* x    = (const float*)d_in[0];
  const float* fr   = (const float*)d_in[1];
  const float* fc   = (const float*)d_in[2];
  const float* bias = (const float*)d_in[3];
  float* out = (float*)d_out;

  if (ws_size >= (size_t)2 * 1024 * 1024) {
    ushort* T = (ushort*)d_ws;
    build_T_kernel<<<dim3(512), dim3(256), 0, stream>>>(fr, fc, T);
    toeplitz_gemm<<<dim3(512), dim3(512), 0, stream>>>(x, T, bias, out);
  } else {
    toeplitz_naive<<<dim3(32768), dim3(256), 0, stream>>>(x, fr, fc, bias, out);
  }
}